// Round 3
// baseline (680.940 us; speedup 1.0000x reference)
//
#include <hip/hip_runtime.h>

// RoutingCapsule: x(16,2048,16) fp32, W(1,2048,64,32,16) fp32, bias(64,32) fp32
// -> v(16,64,32) fp32.   Routing collapses (b_logits additive from 0):
//   s0 = (1/64) sum_i u ; v0 = squash(s0+bias)
//   pass1: c1 = softmax_o(u.v0)      ; s1 = sum_i c1*u
//   pass2: c2 = softmax_o(u.(v0+v1)) ; out = squash(sum_i c2*u + bias)
//
// R9: R8 submission died on "container failed twice" (infra; same
// source-independent mode as R3-R6 of the prior session). Source re-audited:
// all accesses in-bounds (u max idx 67108863/64M, parts 8388607/8M, ws 336MB),
// launch configs legal. Resubmitting unchanged.
// R8 theory (stands): k_uhat 213us @ 2.6TB/s, VALU 9%, occ 33% = latency-bound
// with minimal traffic (560MB -> 89us floor). Fixes: (a) x staged in LDS once
// per block (was 64 broadcast global loads per ii in every thread, vmcnt
// pollution); (b) W register double-buffered (prefetch ii+1 during compute);
// (c) thread owns 1 od -> VGPR ~80, grid 2048, 16 waves/CU.
// k_route: 4 independent waves per 256-thr block (no LDS/sync), 8 i-rows each,
// grid 1024 = 16 waves/CU single round (R7's 64-thr blocks gave only 8 w/CU).
#define B_ 16
#define I_ 2048
#define OD_ 2048
#define EPSQ 1e-9f

typedef float v4f __attribute__((ext_vector_type(4)));

__device__ __forceinline__ float squashf(float s) {
  float sq = s * s;
  return sq / (1.0f + sq) * s * rsqrtf(sq + EPSQ);
}

__device__ __forceinline__ float dot4(v4f a, v4f b) {
  return a.x * b.x + a.y * b.y + a.z * b.z + a.w * b.w;
}

// ---------------------------------------------------------------------------
// K1: u[b,i,od] = sum_p x[b,i,p]*W[i,od,p]  (fp32), plus per-block s0 partials.
// grid=2048: bx&7 = od-eighth e, bx>>3 = i-chunk ic (8 i each).
// Thread owns od = e*256+t. x tile staged in LDS (broadcast); W register
// double-buffered (prefetch ii+1 while computing ii).
// part0[ic][b][od] : 256*16*2048 fp32 = 32 MB.
// ---------------------------------------------------------------------------
__global__ __launch_bounds__(256, 4) void k_uhat(
    const float* __restrict__ x, const float* __restrict__ W,
    float* __restrict__ u, float* __restrict__ part0)
{
  __shared__ float xs[8 * 16 * 16];  // [ii][b][p] 8 KB
  const int t = threadIdx.x;
  const int e = blockIdx.x & 7;
  const int ic = blockIdx.x >> 3;
  const int i0 = ic * 8;
  const int od = e * 256 + t;

  // stage x[b, i0..i0+7, 0..15] -> xs[ii][b][p]. Thread t: b=t>>4, j=t&15,
  // loads floats f=8j..8j+7 of the b-row (128 contiguous floats).
  {
    const int b = t >> 4, j = t & 15;
    const float4* src = (const float4*)(x + (size_t)(b * I_ + i0) * 16);
    float4 a0 = src[j * 2], a1 = src[j * 2 + 1];
    const int ii = j >> 1, pq = (j & 1) * 2;  // float4 slots pq, pq+1 within [ii][b]
    float4* dst = (float4*)xs + ii * 64 + b * 4;
    dst[pq] = a0; dst[pq + 1] = a1;
  }
  __syncthreads();

  float s0acc[B_];
#pragma unroll
  for (int b = 0; b < B_; ++b) s0acc[b] = 0.f;

  const v4f* wb = (const v4f*)(W + ((size_t)i0 * OD_ + od) * 16);
  // stride between consecutive i in v4f units: OD_*16/4 = 8192
  v4f wc[4], wn[4];
#pragma unroll
  for (int k = 0; k < 4; ++k) wc[k] = __builtin_nontemporal_load(wb + k);

  for (int ii = 0; ii < 8; ++ii) {
    if (ii < 7) {
      const v4f* wnp = wb + (size_t)(ii + 1) * 8192;
#pragma unroll
      for (int k = 0; k < 4; ++k) wn[k] = __builtin_nontemporal_load(wnp + k);
    }
    const v4f* xv = (const v4f*)xs + ii * 64;
    float* up = u + (size_t)(i0 + ii) * OD_ + od;
#pragma unroll
    for (int b = 0; b < B_; ++b) {
      v4f x0 = xv[b * 4 + 0], x1 = xv[b * 4 + 1];
      v4f x2 = xv[b * 4 + 2], x3 = xv[b * 4 + 3];
      float s = dot4(x0, wc[0]) + dot4(x1, wc[1]) +
                dot4(x2, wc[2]) + dot4(x3, wc[3]);
      up[(size_t)b * I_ * OD_] = s;
      s0acc[b] += s;
    }
    if (ii < 7) {
#pragma unroll
      for (int k = 0; k < 4; ++k) wc[k] = wn[k];
    }
  }
#pragma unroll
  for (int b = 0; b < B_; ++b)
    part0[((size_t)ic * B_ + b) * OD_ + od] = s0acc[b];
}

// ---------------------------------------------------------------------------
// K2: s0_raw[b,od] = sum_ic part0[ic][b][od].  grid=128: b=bx>>3, od block.
// ---------------------------------------------------------------------------
__global__ __launch_bounds__(256) void k_s0red(
    const float* __restrict__ part0, float* __restrict__ s0)
{
  const int b = blockIdx.x >> 3;
  const int od = (blockIdx.x & 7) * 256 + threadIdx.x;
  float a = 0.f;
  const float* p = part0 + (size_t)b * OD_ + od;
#pragma unroll 8
  for (int ic = 0; ic < 256; ++ic) a += p[(size_t)ic * B_ * OD_];
  s0[b * OD_ + od] = a;
}

// ---------------------------------------------------------------------------
// K3: one routing pass. 256-thr blocks = 4 INDEPENDENT waves (no LDS/sync).
// Wave = (b, g): 8 i-rows. lane = o. vv = squash(sA*scaleA+bias)[+squash(sB+b)].
// Per i: logit = sum_d u*vv; 64-lane softmax over o; acc += c*u (registers).
// Wave writes its own 2048-float partial. grid=1024 (b*64+gblk), g=gblk*4+wv.
// 4 blocks/CU = 16 waves/CU, single round.  part[b*256+g][od] = 32 MB.
// ---------------------------------------------------------------------------
__global__ __launch_bounds__(256, 4) void k_route(
    const float* __restrict__ u,
    const float* __restrict__ sA, float scaleA,
    const float* __restrict__ sB,  // may be null
    const float* __restrict__ bias,
    float* __restrict__ part)
{
  const int t = threadIdx.x;
  const int o = t & 63;
  const int wv = t >> 6;
  const int b = blockIdx.x >> 6;
  const int g = (blockIdx.x & 63) * 4 + wv;
  const int i0 = g * 8;

  v4f vv[8], acc[8];
  {
    const float* sa = sA + b * OD_ + o * 32;
    const float* sb = sB ? sB + b * OD_ + o * 32 : nullptr;
    const float* bp = bias + o * 32;
#pragma unroll
    for (int qq = 0; qq < 8; ++qq) {
#pragma unroll
      for (int j = 0; j < 4; ++j) {
        float bs = bp[qq * 4 + j];
        float val = squashf(sa[qq * 4 + j] * scaleA + bs);
        if (sb) val += squashf(sb[qq * 4 + j] + bs);
        vv[qq][j] = val;
      }
      v4f z = {0.f, 0.f, 0.f, 0.f};
      acc[qq] = z;
    }
  }

  for (int ii = 0; ii < 8; ++ii) {
    const int i = i0 + ii;
    const v4f* up = (const v4f*)(u + (size_t)(b * I_ + i) * OD_ + o * 32);
    v4f r[8];
#pragma unroll
    for (int qq = 0; qq < 8; ++qq) r[qq] = up[qq];

    float logit = 0.f;
#pragma unroll
    for (int qq = 0; qq < 8; ++qq)
#pragma unroll
      for (int j = 0; j < 4; ++j)
        logit = fmaf(r[qq][j], vv[qq][j], logit);

    float m = logit;
#pragma unroll
    for (int off = 32; off > 0; off >>= 1) m = fmaxf(m, __shfl_xor(m, off, 64));
    float ex = __expf(logit - m);
    float sm = ex;
#pragma unroll
    for (int off = 32; off > 0; off >>= 1) sm += __shfl_xor(sm, off, 64);
    float c = ex * __builtin_amdgcn_rcpf(sm);

#pragma unroll
    for (int qq = 0; qq < 8; ++qq)
#pragma unroll
      for (int j = 0; j < 4; ++j)
        acc[qq][j] = fmaf(c, r[qq][j], acc[qq][j]);
  }

  v4f* pp = (v4f*)(part + (size_t)(b * 256 + g) * OD_ + o * 32);
#pragma unroll
  for (int qq = 0; qq < 8; ++qq) pp[qq] = acc[qq];
}

// ---------------------------------------------------------------------------
// K4: s1[b,od] = sum_g part[(b*256+g)][od].  grid=128.
// ---------------------------------------------------------------------------
__global__ __launch_bounds__(256) void k_s1red(
    const float* __restrict__ part, float* __restrict__ s1)
{
  const int b = blockIdx.x >> 3;
  const int od = (blockIdx.x & 7) * 256 + threadIdx.x;
  float a = 0.f;
  const float* p = part + (size_t)b * 256 * OD_ + od;
#pragma unroll 8
  for (int g = 0; g < 256; ++g) a += p[(size_t)g * OD_];
  s1[b * OD_ + od] = a;
}

// ---------------------------------------------------------------------------
// K5: out[b,od] = squash(sum_g part2 + bias).  grid=128.
// ---------------------------------------------------------------------------
__global__ __launch_bounds__(256) void k_outred(
    const float* __restrict__ part, const float* __restrict__ bias,
    float* __restrict__ out)
{
  const int b = blockIdx.x >> 3;
  const int od = (blockIdx.x & 7) * 256 + threadIdx.x;
  float a = 0.f;
  const float* p = part + (size_t)b * 256 * OD_ + od;
#pragma unroll 8
  for (int g = 0; g < 256; ++g) a += p[(size_t)g * OD_];
  out[b * OD_ + od] = squashf(a + bias[od]);
}

extern "C" void kernel_launch(void* const* d_in, const int* in_sizes, int n_in,
                              void* d_out, int out_size, void* d_ws, size_t ws_size,
                              hipStream_t stream) {
  const float* x = (const float*)d_in[0];
  const float* W = (const float*)d_in[1];
  const float* bias = (const float*)d_in[2];
  float* out = (float*)d_out;

  char* ws = (char*)d_ws;
  float* u_ws  = (float*)ws;                          // 256 MB fp32 u_hat
  float* part0 = (float*)(ws + 268435456ull);         // 32 MB s0 partials
  float* part1 = (float*)(ws + 301989888ull);         // 32 MB route partials
  float* part2 = part0;                               // reuse: part0 dead after K2
  float* s0    = (float*)(ws + 335544320ull);         // 128 KB
  float* s1    = s0 + 32768;                          // 128 KB

  k_uhat <<<dim3(2048), dim3(256), 0, stream>>>(x, W, u_ws, part0);
  k_s0red<<<dim3(128),  dim3(256), 0, stream>>>(part0, s0);
  // pass1: v0 = squash(s0/64 + bias)
  k_route<<<dim3(1024), dim3(256), 0, stream>>>(u_ws, s0, 1.0f / 64.0f, nullptr, bias, part1);
  k_s1red<<<dim3(128),  dim3(256), 0, stream>>>(part1, s1);
  // pass2: vv = squash(s0/64+bias) + squash(s1+bias)
  k_route<<<dim3(1024), dim3(256), 0, stream>>>(u_ws, s0, 1.0f / 64.0f, s1, bias, part2);
  k_outred<<<dim3(128), dim3(256), 0, stream>>>(part2, bias, out);
}

// Round 4
// 630.015 us; speedup vs baseline: 1.0808x; 1.0808x over previous
//
#include <hip/hip_runtime.h>

// RoutingCapsule: x(16,2048,16) fp32, W(1,2048,64,32,16) fp32, bias(64,32) fp32
// -> v(16,64,32) fp32.   Routing collapses (b_logits additive from 0):
//   s0 = (1/64) sum_i u ; v0 = squash(s0+bias)
//   pass1: c1 = softmax_o(u.v0)      ; s1 = sum_i c1*u
//   pass2: c2 = softmax_o(u.(v0+v1)) ; out = squash(sum_i c2*u + bias)
//
// R10: u_hat is NEVER materialized. R9 post-mortem: ~316us of dur is harness
// poison fills; controllable ~365us vs 190us floor, and 768MB of the 1.18GB
// traffic was u (256w + 512r). The einsum is only 2.1 GFLOP (~14us at fp32
// vector peak) -> recompute u inside each routing pass:
//  - k_s0sweep: R9's k_uhat minus the u store (W 256MB read + 32MB partials).
//  - k_rsweep (x2): streams W once per pass. 256 blocks x 512thr (8 waves,
//    1 block/CU). Per i: 128KB W row staged to LDS as two 64KB d-halves
//    (d 0..15 / 16..31 so every lane(=o) has data in both halves), double-
//    buffered global_load_lds(16B). Padded layout slot = o*65 + d*4 + q:
//    stride 65 == 1 mod 8 -> conflict-free ds_read_b128 AND linear per-
//    instruction dest (no swizzle; pad falls between instructions).
//    Wave owns 2 b; x -> SGPR via readfirstlane; u in regs through
//    logit -> softmax -> acc, so W read exactly once per pass. VGPR ~235.
// Traffic 1.18GB -> ~0.87GB. Reducers + partial layouts unchanged.
#define B_ 16
#define I_ 2048
#define OD_ 2048
#define EPSQ 1e-9f

typedef float v4f __attribute__((ext_vector_type(4)));

__device__ __forceinline__ float squashf(float s) {
  float sq = s * s;
  return sq / (1.0f + sq) * s * rsqrtf(sq + EPSQ);
}

__device__ __forceinline__ float dot4(v4f a, v4f b) {
  return a.x * b.x + a.y * b.y + a.z * b.z + a.w * b.w;
}

__device__ __forceinline__ void gload16(const void* g, void* l) {
  __builtin_amdgcn_global_load_lds(
      (__attribute__((address_space(1))) const unsigned int*)g,
      (__attribute__((address_space(3))) unsigned int*)l, 16, 0, 0);
}

__device__ __forceinline__ float rfl(float v) {
  return __uint_as_float(__builtin_amdgcn_readfirstlane(__float_as_uint(v)));
}

// ---------------------------------------------------------------------------
// K1: s0 partials only (no u materialization).
// grid=2048: bx&7 = od-eighth e, bx>>3 = i-chunk ic (8 i each). Thread owns
// od = e*256+t. x staged in LDS; W register double-buffered.
// part0[ic][b][od] : 256*16*2048 fp32 = 32 MB.
// ---------------------------------------------------------------------------
__global__ __launch_bounds__(256, 4) void k_s0sweep(
    const float* __restrict__ x, const float* __restrict__ W,
    float* __restrict__ part0)
{
  __shared__ float xs[8 * 16 * 16];  // [ii][b][p] 8 KB
  const int t = threadIdx.x;
  const int e = blockIdx.x & 7;
  const int ic = blockIdx.x >> 3;
  const int i0 = ic * 8;
  const int od = e * 256 + t;

  {
    const int b = t >> 4, j = t & 15;
    const float4* src = (const float4*)(x + (size_t)(b * I_ + i0) * 16);
    float4 a0 = src[j * 2], a1 = src[j * 2 + 1];
    const int ii = j >> 1, pq = (j & 1) * 2;
    float4* dst = (float4*)xs + ii * 64 + b * 4;
    dst[pq] = a0; dst[pq + 1] = a1;
  }
  __syncthreads();

  float s0acc[B_];
#pragma unroll
  for (int b = 0; b < B_; ++b) s0acc[b] = 0.f;

  const v4f* wb = (const v4f*)(W + ((size_t)i0 * OD_ + od) * 16);
  v4f wc[4], wn[4];
#pragma unroll
  for (int k = 0; k < 4; ++k) wc[k] = __builtin_nontemporal_load(wb + k);

  for (int ii = 0; ii < 8; ++ii) {
    if (ii < 7) {
      const v4f* wnp = wb + (size_t)(ii + 1) * 8192;
#pragma unroll
      for (int k = 0; k < 4; ++k) wn[k] = __builtin_nontemporal_load(wnp + k);
    }
    const v4f* xv = (const v4f*)xs + ii * 64;
#pragma unroll
    for (int b = 0; b < B_; ++b) {
      v4f x0 = xv[b * 4 + 0], x1 = xv[b * 4 + 1];
      v4f x2 = xv[b * 4 + 2], x3 = xv[b * 4 + 3];
      s0acc[b] += dot4(x0, wc[0]) + dot4(x1, wc[1]) +
                  dot4(x2, wc[2]) + dot4(x3, wc[3]);
    }
    if (ii < 7) {
#pragma unroll
      for (int k = 0; k < 4; ++k) wc[k] = wn[k];
    }
  }
#pragma unroll
  for (int b = 0; b < B_; ++b)
    part0[((size_t)ic * B_ + b) * OD_ + od] = s0acc[b];
}

// ---------------------------------------------------------------------------
// K2: s0_raw[b,od] = sum_ic part0[ic][b][od].  grid=128.
// ---------------------------------------------------------------------------
__global__ __launch_bounds__(256) void k_s0red(
    const float* __restrict__ part0, float* __restrict__ s0)
{
  const int b = blockIdx.x >> 3;
  const int od = (blockIdx.x & 7) * 256 + threadIdx.x;
  float a = 0.f;
  const float* p = part0 + (size_t)b * OD_ + od;
#pragma unroll 8
  for (int ic = 0; ic < 256; ++ic) a += p[(size_t)ic * B_ * OD_];
  s0[b * OD_ + od] = a;
}

// ---------------------------------------------------------------------------
// K3: fused routing sweep — recomputes u from W/x, W streamed exactly once.
// 256 blocks x 512 thr (8 waves, 1 block/CU, LDS 130KB). Block owns 8 i.
// Wave wv owns b = 2wv, 2wv+1; lane = o. Per i: W row staged in two 64KB
// d-halves, double-buffered; u kept in regs; exact softmax per (b,i); acc
// accumulated over the block's 8 i; one 8KB partial write per (wave,b).
// part[(b*256 + blk)][od] : 32 MB.
// ---------------------------------------------------------------------------
__global__ __launch_bounds__(512, 2) void k_rsweep(
    const float* __restrict__ x, const float* __restrict__ W,
    const float* __restrict__ sA, float scaleA,
    const float* __restrict__ sB,  // may be null
    const float* __restrict__ bias,
    float* __restrict__ part)
{
  __shared__ float4 bufA[64 * 65];  // 66560 B
  __shared__ float4 bufB[64 * 65];  // 66560 B
  const int t = threadIdx.x;
  const int o = t & 63;
  const int wv = t >> 6;
  const int i0 = blockIdx.x * 8;

  // vv = squash(sA*scaleA + bias) [+ squash(sB + bias)], per (bb, d)
  float vvA[2][16], vvB[2][16];
#pragma unroll
  for (int bb = 0; bb < 2; ++bb) {
    const int b = wv * 2 + bb;
    const float* sa = sA + b * OD_ + o * 32;
    const float* sb = sB ? sB + b * OD_ + o * 32 : nullptr;
    const float* bp = bias + o * 32;
#pragma unroll
    for (int d = 0; d < 16; ++d) {
      float bs0 = bp[d], bs1 = bp[d + 16];
      float va = squashf(sa[d] * scaleA + bs0);
      float vb = squashf(sa[d + 16] * scaleA + bs1);
      if (sb) { va += squashf(sb[d] + bs0); vb += squashf(sb[d + 16] + bs1); }
      vvA[bb][d] = va; vvB[bb][d] = vb;
    }
  }

  float accA[2][16], accB[2][16];
#pragma unroll
  for (int bb = 0; bb < 2; ++bb)
#pragma unroll
    for (int d = 0; d < 16; ++d) { accA[bb][d] = 0.f; accB[bb][d] = 0.f; }

  // ---- staging helper (inlined twice): wave stages 8 o-slices of a half ----
#define STAGE_HALF(row, half, buf)                                         \
  {                                                                        \
    const float* rp = (row) + (half) * 256 + o % 64 * 0; /* keep o use */  \
    _Pragma("unroll")                                                      \
    for (int k = 0; k < 8; ++k) {                                          \
      const int oo = wv + k * 8;                                           \
      const float* g = (row) + oo * 512 + (half) * 256 + (t & 63) * 4;     \
      gload16(g, (void*)((char*)(buf) + (size_t)(oo * 65) * 16));          \
    }                                                                      \
    (void)rp;                                                              \
  }

  // prologue: A(0) staged+drained; B(0) in flight
  const float* Wrow0 = W + (size_t)i0 * (OD_ * 16);
  STAGE_HALF(Wrow0, 0, bufA);
  __syncthreads();
  STAGE_HALF(Wrow0, 1, bufB);

  for (int ii = 0; ii < 8; ++ii) {
    const int i = i0 + ii;
    const float* Wnext = W + (size_t)(i + 1) * (OD_ * 16);

    // x -> SGPRs (uniform per wave-iteration)
    float xsv[2][16];
#pragma unroll
    for (int bb = 0; bb < 2; ++bb) {
      const float4* xp = (const float4*)(x + ((size_t)((wv * 2 + bb) * I_) + i) * 16);
#pragma unroll
      for (int q = 0; q < 4; ++q) {
        float4 xq = xp[q];
        xsv[bb][q * 4 + 0] = rfl(xq.x); xsv[bb][q * 4 + 1] = rfl(xq.y);
        xsv[bb][q * 4 + 2] = rfl(xq.z); xsv[bb][q * 4 + 3] = rfl(xq.w);
      }
    }

    float lg[2] = {0.f, 0.f};
    float uA[2][16], uB[2][16];

    // ---- compute half A (d = 0..15) from bufA ----
#pragma unroll
    for (int d = 0; d < 16; ++d) {
      const float4* wp = bufA + o * 65 + d * 4;
      float4 w0 = wp[0], w1 = wp[1], w2 = wp[2], w3 = wp[3];
#pragma unroll
      for (int bb = 0; bb < 2; ++bb) {
        float uu = xsv[bb][0] * w0.x;
        uu = fmaf(xsv[bb][1], w0.y, uu); uu = fmaf(xsv[bb][2], w0.z, uu);
        uu = fmaf(xsv[bb][3], w0.w, uu); uu = fmaf(xsv[bb][4], w1.x, uu);
        uu = fmaf(xsv[bb][5], w1.y, uu); uu = fmaf(xsv[bb][6], w1.z, uu);
        uu = fmaf(xsv[bb][7], w1.w, uu); uu = fmaf(xsv[bb][8], w2.x, uu);
        uu = fmaf(xsv[bb][9], w2.y, uu); uu = fmaf(xsv[bb][10], w2.z, uu);
        uu = fmaf(xsv[bb][11], w2.w, uu); uu = fmaf(xsv[bb][12], w3.x, uu);
        uu = fmaf(xsv[bb][13], w3.y, uu); uu = fmaf(xsv[bb][14], w3.z, uu);
        uu = fmaf(xsv[bb][15], w3.w, uu);
        uA[bb][d] = uu;
        lg[bb] = fmaf(uu, vvA[bb][d], lg[bb]);
      }
    }
    __syncthreads();                 // bufB(ii) complete; all done with bufA
    if (ii < 7) STAGE_HALF(Wnext, 0, bufA);

    // ---- compute half B (d = 16..31) from bufB ----
#pragma unroll
    for (int d = 0; d < 16; ++d) {
      const float4* wp = bufB + o * 65 + d * 4;
      float4 w0 = wp[0], w1 = wp[1], w2 = wp[2], w3 = wp[3];
#pragma unroll
      for (int bb = 0; bb < 2; ++bb) {
        float uu = xsv[bb][0] * w0.x;
        uu = fmaf(xsv[bb][1], w0.y, uu); uu = fmaf(xsv[bb][2], w0.z, uu);
        uu = fmaf(xsv[bb][3], w0.w, uu); uu = fmaf(xsv[bb][4], w1.x, uu);
        uu = fmaf(xsv[bb][5], w1.y, uu); uu = fmaf(xsv[bb][6], w1.z, uu);
        uu = fmaf(xsv[bb][7], w1.w, uu); uu = fmaf(xsv[bb][8], w2.x, uu);
        uu = fmaf(xsv[bb][9], w2.y, uu); uu = fmaf(xsv[bb][10], w2.z, uu);
        uu = fmaf(xsv[bb][11], w2.w, uu); uu = fmaf(xsv[bb][12], w3.x, uu);
        uu = fmaf(xsv[bb][13], w3.y, uu); uu = fmaf(xsv[bb][14], w3.z, uu);
        uu = fmaf(xsv[bb][15], w3.w, uu);
        uB[bb][d] = uu;
        lg[bb] = fmaf(uu, vvB[bb][d], lg[bb]);
      }
    }

    // ---- exact softmax over o (64 lanes) per bb, then accumulate ----
#pragma unroll
    for (int bb = 0; bb < 2; ++bb) {
      float m = lg[bb];
#pragma unroll
      for (int off = 32; off > 0; off >>= 1) m = fmaxf(m, __shfl_xor(m, off, 64));
      float ex = __expf(lg[bb] - m);
      float sm = ex;
#pragma unroll
      for (int off = 32; off > 0; off >>= 1) sm += __shfl_xor(sm, off, 64);
      float c = ex * __builtin_amdgcn_rcpf(sm);
#pragma unroll
      for (int d = 0; d < 16; ++d) {
        accA[bb][d] = fmaf(c, uA[bb][d], accA[bb][d]);
        accB[bb][d] = fmaf(c, uB[bb][d], accB[bb][d]);
      }
    }
    __syncthreads();                 // bufA(ii+1) complete; all done with bufB
    if (ii < 7) STAGE_HALF(Wnext, 1, bufB);
  }

  // ---- write per-(wave,b) partial: part[(b*256 + blk)][o*32 + d] ----
#pragma unroll
  for (int bb = 0; bb < 2; ++bb) {
    const int b = wv * 2 + bb;
    float4* dst = (float4*)(part + ((size_t)(b * 256 + blockIdx.x)) * OD_ + o * 32);
#pragma unroll
    for (int q = 0; q < 4; ++q) {
      float4 v0, v1;
      v0.x = accA[bb][q * 4 + 0]; v0.y = accA[bb][q * 4 + 1];
      v0.z = accA[bb][q * 4 + 2]; v0.w = accA[bb][q * 4 + 3];
      v1.x = accB[bb][q * 4 + 0]; v1.y = accB[bb][q * 4 + 1];
      v1.z = accB[bb][q * 4 + 2]; v1.w = accB[bb][q * 4 + 3];
      dst[q] = v0; dst[q + 4] = v1;
    }
  }
}

// ---------------------------------------------------------------------------
// K4: s1[b,od] = sum_g part[(b*256+g)][od].  grid=128.
// ---------------------------------------------------------------------------
__global__ __launch_bounds__(256) void k_s1red(
    const float* __restrict__ part, float* __restrict__ s1)
{
  const int b = blockIdx.x >> 3;
  const int od = (blockIdx.x & 7) * 256 + threadIdx.x;
  float a = 0.f;
  const float* p = part + (size_t)b * 256 * OD_ + od;
#pragma unroll 8
  for (int g = 0; g < 256; ++g) a += p[(size_t)g * OD_];
  s1[b * OD_ + od] = a;
}

// ---------------------------------------------------------------------------
// K5: out[b,od] = squash(sum_g part2 + bias).  grid=128.
// ---------------------------------------------------------------------------
__global__ __launch_bounds__(256) void k_outred(
    const float* __restrict__ part, const float* __restrict__ bias,
    float* __restrict__ out)
{
  const int b = blockIdx.x >> 3;
  const int od = (blockIdx.x & 7) * 256 + threadIdx.x;
  float a = 0.f;
  const float* p = part + (size_t)b * 256 * OD_ + od;
#pragma unroll 8
  for (int g = 0; g < 256; ++g) a += p[(size_t)g * OD_];
  out[b * OD_ + od] = squashf(a + bias[od]);
}

extern "C" void kernel_launch(void* const* d_in, const int* in_sizes, int n_in,
                              void* d_out, int out_size, void* d_ws, size_t ws_size,
                              hipStream_t stream) {
  const float* x = (const float*)d_in[0];
  const float* W = (const float*)d_in[1];
  const float* bias = (const float*)d_in[2];
  float* out = (float*)d_out;

  char* ws = (char*)d_ws;
  float* part0 = (float*)ws;                          // 32 MB s0 partials
  float* part1 = (float*)(ws + 33554432ull);          // 32 MB route partials
  float* part2 = part0;                               // reuse: part0 dead after K2
  float* s0    = (float*)(ws + 67108864ull);          // 128 KB
  float* s1    = s0 + 32768;                          // 128 KB

  k_s0sweep<<<dim3(2048), dim3(256), 0, stream>>>(x, W, part0);
  k_s0red  <<<dim3(128),  dim3(256), 0, stream>>>(part0, s0);
  // pass1: v0 = squash(s0/64 + bias)
  k_rsweep <<<dim3(256),  dim3(512), 0, stream>>>(x, W, s0, 1.0f / 64.0f, nullptr, bias, part1);
  k_s1red  <<<dim3(128),  dim3(256), 0, stream>>>(part1, s1);
  // pass2: vv = squash(s0/64+bias) + squash(s1+bias)
  k_rsweep <<<dim3(256),  dim3(512), 0, stream>>>(x, W, s0, 1.0f / 64.0f, s1, bias, part2);
  k_outred <<<dim3(128),  dim3(256), 0, stream>>>(part2, bias, out);
}